// Round 3
// baseline (258.140 us; speedup 1.0000x reference)
//
#include <hip/hip_runtime.h>
#include <hip/hip_bf16.h>
#include <math.h>

// Problem constants
#define NN 4096
#define FF 256
#define KH 4
#define FP 64
#define NCOL 256   // K*FP
#define MAXNBR 512

// bf16 -> f32 exact upcast
__device__ __forceinline__ float bits2f(unsigned b) {
    union { unsigned u; float f; } c; c.u = b << 16; return c.f;
}

// Workspace layout (bytes)
#define OFF_SUMS   0            // double[2]
#define OFF_FLAG   16           // int
#define OFF_XF     128          // f32[1048576]  (4 MB)
#define OFF_WF     4194432      // f32[65536] row-major (256 KB)
#define OFF_BIAS   4456576      // f32[256]
#define OFF_AL     4457600      // f32[256]
#define OFF_AR     4458624      // f32[256]
#define OFF_XP     4459648      // f32[1048576] (4 MB)
#define OFF_SRC    8653952      // f32[16384]
#define OFF_TGT    8719488      // f32[16384]
#define OFF_NBR    8785024      // u16[4096*512] (4 MB)
#define OFF_CNT    12979328     // i32[4096]

// ---- kernel 0: dtype sniff + zero accumulators -------------------------------
// mask[0,0] == 1.0 exactly. fp32 -> first u32 = 0x3F800000.
// bf16 -> first u32 = 0x00003F80 or 0x3F803F80. Distinguishable.
__global__ void k_detect(const unsigned* __restrict__ mask_raw,
                         int* __restrict__ flag, double* __restrict__ sums) {
    if (threadIdx.x == 0) {
        *flag = (mask_raw[0] == 0x3F800000u) ? 1 : 0;   // 1 = fp32 inputs
        sums[0] = 0.0;
        sums[1] = 0.0;
    }
}

// ---- kernel 1: x -> f32 workspace (copy or upcast) ---------------------------
__global__ __launch_bounds__(256) void k_cvt_x(
        const void* __restrict__ xr, const int* __restrict__ flag,
        float* __restrict__ xf) {
    int i = blockIdx.x * 256 + threadIdx.x;    // 262144 quads
    float4 v;
    if (*flag) {
        v = ((const float4*)xr)[i];
    } else {
        ushort4 u = ((const ushort4*)xr)[i];
        v.x = bits2f(u.x); v.y = bits2f(u.y); v.z = bits2f(u.z); v.w = bits2f(u.w);
    }
    ((float4*)xf)[i] = v;
}

// ---- kernel 2: W (row-major, no transpose) + b / a_left / a_right to f32 -----
__global__ __launch_bounds__(256) void k_cvt_w(
        const void* __restrict__ Wr, const void* __restrict__ br,
        const void* __restrict__ alr, const void* __restrict__ arr,
        const int* __restrict__ flag,
        float* __restrict__ WF, float* __restrict__ bias_f,
        float* __restrict__ al_f, float* __restrict__ ar_f) {
    int idx = blockIdx.x * 256 + threadIdx.x;   // 65536
    int fl = *flag;
    WF[idx] = fl ? ((const float*)Wr)[idx] : bits2f(((const unsigned short*)Wr)[idx]);
    if (idx < NCOL) {
        bias_f[idx] = fl ? ((const float*)br)[idx]  : bits2f(((const unsigned short*)br)[idx]);
        al_f[idx]   = fl ? ((const float*)alr)[idx] : bits2f(((const unsigned short*)alr)[idx]);
        ar_f[idx]   = fl ? ((const float*)arr)[idx] : bits2f(((const unsigned short*)arr)[idx]);
    }
}

// ---- kernel 3: per-row neighbor lists from the mask --------------------------
__global__ __launch_bounds__(256) void k_rows(
        const void* __restrict__ mask, const int* __restrict__ flag,
        unsigned short* __restrict__ nbr_g, int* __restrict__ cnt_g) {
    __shared__ int cnt;
    int n = blockIdx.x;
    if (threadIdx.x == 0) cnt = 0;
    __syncthreads();
    unsigned short* rn = nbr_g + (size_t)n * MAXNBR;
    if (*flag) {
        const uint4* p = (const uint4*)((const float*)mask + (size_t)n * NN);
        for (int i = threadIdx.x; i < NN / 4; i += 256) {
            uint4 v = p[i]; int base = i * 4;
            if (v.x) { int s = atomicAdd(&cnt, 1); if (s < MAXNBR) rn[s] = base + 0; }
            if (v.y) { int s = atomicAdd(&cnt, 1); if (s < MAXNBR) rn[s] = base + 1; }
            if (v.z) { int s = atomicAdd(&cnt, 1); if (s < MAXNBR) rn[s] = base + 2; }
            if (v.w) { int s = atomicAdd(&cnt, 1); if (s < MAXNBR) rn[s] = base + 3; }
        }
    } else {
        const uint4* p = (const uint4*)((const unsigned short*)mask + (size_t)n * NN);
        for (int i = threadIdx.x; i < NN / 8; i += 256) {
            uint4 v = p[i]; int base = i * 8;
            if (v.x & 0xFFFFu) { int s = atomicAdd(&cnt, 1); if (s < MAXNBR) rn[s] = base + 0; }
            if (v.x >> 16)     { int s = atomicAdd(&cnt, 1); if (s < MAXNBR) rn[s] = base + 1; }
            if (v.y & 0xFFFFu) { int s = atomicAdd(&cnt, 1); if (s < MAXNBR) rn[s] = base + 2; }
            if (v.y >> 16)     { int s = atomicAdd(&cnt, 1); if (s < MAXNBR) rn[s] = base + 3; }
            if (v.z & 0xFFFFu) { int s = atomicAdd(&cnt, 1); if (s < MAXNBR) rn[s] = base + 4; }
            if (v.z >> 16)     { int s = atomicAdd(&cnt, 1); if (s < MAXNBR) rn[s] = base + 5; }
            if (v.w & 0xFFFFu) { int s = atomicAdd(&cnt, 1); if (s < MAXNBR) rn[s] = base + 6; }
            if (v.w >> 16)     { int s = atomicAdd(&cnt, 1); if (s < MAXNBR) rn[s] = base + 7; }
        }
    }
    __syncthreads();
    if (threadIdx.x == 0) cnt_g[n] = cnt < MAXNBR ? cnt : MAXNBR;
}

// ---- kernel 4: x_proj = x @ W + b, plain fp32 VALU GEMM ----------------------
// 512 blocks x 256 threads; each block does 8 rows, each thread one output col.
__global__ __launch_bounds__(256) void gat_gemm_valu(
        const float* __restrict__ xf, const float* __restrict__ WF,
        const float* __restrict__ bias, float* __restrict__ xp) {
    __shared__ float4 xs[8][64];
    int n0 = blockIdx.x * 8;
    for (int t = threadIdx.x; t < 512; t += 256) {
        int r = t >> 6, q = t & 63;
        xs[r][q] = ((const float4*)(xf + (size_t)(n0 + r) * FF))[q];
    }
    __syncthreads();
    int c = threadIdx.x;
    float acc[8] = {};
    for (int kk = 0; kk < 64; ++kk) {
        float w0 = WF[(4 * kk + 0) * NCOL + c];
        float w1 = WF[(4 * kk + 1) * NCOL + c];
        float w2 = WF[(4 * kk + 2) * NCOL + c];
        float w3 = WF[(4 * kk + 3) * NCOL + c];
        #pragma unroll
        for (int r = 0; r < 8; ++r) {
            float4 xv = xs[r][kk];
            acc[r] += xv.x * w0 + xv.y * w1 + xv.z * w2 + xv.w * w3;
        }
    }
    float bv = bias[c];
    #pragma unroll
    for (int r = 0; r < 8; ++r)
        xp[(size_t)(n0 + r) * NCOL + c] = acc[r] + bv;
}

// ---- kernel 5: src/tgt attention dots, one wave per node ---------------------
__global__ __launch_bounds__(256) void gat_scores(
        const float* __restrict__ xp,
        const float* __restrict__ alf, const float* __restrict__ arf,
        float* __restrict__ src, float* __restrict__ tgt) {
    int wave = threadIdx.x >> 6, lane = threadIdx.x & 63;
    int n = blockIdx.x * 4 + wave;
    float s[KH], t[KH];
    #pragma unroll
    for (int k = 0; k < KH; ++k) {
        float v = xp[n * NCOL + k * FP + lane];
        s[k] = v * alf[k * FP + lane];
        t[k] = v * arf[k * FP + lane];
    }
    #pragma unroll
    for (int off = 32; off; off >>= 1) {
        #pragma unroll
        for (int k = 0; k < KH; ++k) {
            s[k] += __shfl_down(s[k], off, 64);
            t[k] += __shfl_down(t[k], off, 64);
        }
    }
    if (lane == 0) {
        #pragma unroll
        for (int k = 0; k < KH; ++k) {
            src[n * KH + k] = s[k];
            tgt[n * KH + k] = t[k];
        }
    }
}

// ---- kernel 6: global moments of lrelu(src_n + tgt_m) over all 67M values ----
__global__ __launch_bounds__(256) void gat_moments(
        const float* __restrict__ src, const float* __restrict__ tgt,
        double* __restrict__ sums) {
    const int total = NN * NN;
    int stride = gridDim.x * blockDim.x;
    float s1 = 0.f, s2 = 0.f;
    for (int p = blockIdx.x * blockDim.x + threadIdx.x; p < total; p += stride) {
        int n = p >> 12, m = p & 4095;
        float4 sv = ((const float4*)src)[n];
        float4 tv = ((const float4*)tgt)[m];
        float v0 = sv.x + tv.x; v0 = v0 > 0.f ? v0 : 0.2f * v0;
        float v1 = sv.y + tv.y; v1 = v1 > 0.f ? v1 : 0.2f * v1;
        float v2 = sv.z + tv.z; v2 = v2 > 0.f ? v2 : 0.2f * v2;
        float v3 = sv.w + tv.w; v3 = v3 > 0.f ? v3 : 0.2f * v3;
        s1 += v0 + v1 + v2 + v3;
        s2 += v0 * v0 + v1 * v1 + v2 * v2 + v3 * v3;
    }
    __shared__ double l1[256], l2[256];
    l1[threadIdx.x] = (double)s1;
    l2[threadIdx.x] = (double)s2;
    __syncthreads();
    for (int off = 128; off; off >>= 1) {
        if (threadIdx.x < off) {
            l1[threadIdx.x] += l1[threadIdx.x + off];
            l2[threadIdx.x] += l2[threadIdx.x + off];
        }
        __syncthreads();
    }
    if (threadIdx.x == 0) {
        atomicAdd(&sums[0], l1[0]);
        atomicAdd(&sums[1], l2[0]);
    }
}

// ---- kernel 7: per-row sparse softmax + aggregation + ELU (fp32 out) ---------
__global__ __launch_bounds__(256) void gat_aggregate(
        const unsigned short* __restrict__ nbr_g, const int* __restrict__ cnt_g,
        const float* __restrict__ xp,
        const float* __restrict__ src, const float* __restrict__ tgt,
        const double* __restrict__ sums,
        float* __restrict__ out) {
    __shared__ unsigned short snbr[MAXNBR];
    __shared__ float pls[MAXNBR * KH];
    __shared__ float invden[KH];
    int n = blockIdx.x;
    int c = cnt_g[n];
    for (int j = threadIdx.x; j < c; j += 256) snbr[j] = nbr_g[(size_t)n * MAXNBR + j];
    __syncthreads();

    double s = sums[0], ss = sums[1];
    const double tot = (double)NN * (double)NN * (double)KH;
    float mu = (float)(s / tot);
    float inv_sigma = (float)(1.0 / sqrt((ss - s * s / tot) / (tot - 1.0)));

    for (int t = threadIdx.x; t < c * KH; t += 256) {
        int j = t >> 2, k = t & 3;
        int m = snbr[j];
        float v = src[n * KH + k] + tgt[m * KH + k];
        v = v > 0.f ? v : 0.2f * v;
        pls[j * KH + k] = expf((v - mu) * inv_sigma);
    }
    __syncthreads();
    if (threadIdx.x < KH) {
        float d = 0.f;
        for (int j = 0; j < c; ++j) d += pls[j * KH + threadIdx.x];
        invden[threadIdx.x] = 1.0f / d;
    }
    __syncthreads();

    int col = threadIdx.x;
    int k = col >> 6;
    float acc = 0.f;
    for (int j = 0; j < c; ++j) {
        acc += pls[j * KH + k] * xp[(size_t)snbr[j] * NCOL + col];
    }
    acc *= invden[k];
    float o = acc > 0.f ? acc : expm1f(acc);
    out[(size_t)n * NCOL + col] = o;
}

extern "C" void kernel_launch(void* const* d_in, const int* in_sizes, int n_in,
                              void* d_out, int out_size, void* d_ws, size_t ws_size,
                              hipStream_t stream) {
    const void* x    = d_in[0];
    const void* mask = d_in[1];
    // d_in[2] = batch (int32) — unused by the reference math
    const void* W    = d_in[3];
    const void* b    = d_in[4];
    const void* al   = d_in[5];
    const void* ar   = d_in[6];

    char* ws = (char*)d_ws;
    double* sums = (double*)(ws + OFF_SUMS);
    int* flag = (int*)(ws + OFF_FLAG);
    float* xf   = (float*)(ws + OFF_XF);
    float* WF   = (float*)(ws + OFF_WF);
    float* bias = (float*)(ws + OFF_BIAS);
    float* alf  = (float*)(ws + OFF_AL);
    float* arf  = (float*)(ws + OFF_AR);
    float* xp   = (float*)(ws + OFF_XP);
    float* src  = (float*)(ws + OFF_SRC);
    float* tgt  = (float*)(ws + OFF_TGT);
    unsigned short* nbr = (unsigned short*)(ws + OFF_NBR);
    int* cntg = (int*)(ws + OFF_CNT);

    k_detect<<<1, 64, 0, stream>>>((const unsigned*)mask, flag, sums);
    k_cvt_x<<<1024, 256, 0, stream>>>(x, flag, xf);
    k_cvt_w<<<256, 256, 0, stream>>>(W, b, al, ar, flag, WF, bias, alf, arf);
    k_rows<<<4096, 256, 0, stream>>>(mask, flag, nbr, cntg);
    gat_gemm_valu<<<512, 256, 0, stream>>>(xf, WF, bias, xp);
    gat_scores<<<1024, 256, 0, stream>>>(xp, alf, arf, src, tgt);
    gat_moments<<<4096, 256, 0, stream>>>(src, tgt, sums);
    gat_aggregate<<<4096, 256, 0, stream>>>(nbr, cntg, xp, src, tgt, sums,
                                            (float*)d_out);
}

// Round 4
// 170.417 us; speedup vs baseline: 1.5148x; 1.5148x over previous
//
#include <hip/hip_runtime.h>
#include <hip/hip_bf16.h>
#include <math.h>

// Problem constants
#define NN 4096
#define FF 256
#define KH 4
#define FP 64
#define NCOL 256   // K*FP
#define MAXNBR 512
#define MOM_BLOCKS 2048

// bf16 -> f32 exact upcast
__device__ __forceinline__ float bits2f(unsigned b) {
    union { unsigned u; float f; } c; c.u = b << 16; return c.f;
}

// Workspace layout (bytes)
#define OFF_SUMS   0            // double[2]
#define OFF_FLAG   16           // int
#define OFF_PART   128          // double2[2048] (32 KB) — reuses old XF slot
#define OFF_WF     4194432      // f32[65536] row-major (256 KB)
#define OFF_BIAS   4456576      // f32[256]
#define OFF_AL     4457600      // f32[256]
#define OFF_AR     4458624      // f32[256]
#define OFF_XP     4459648      // f32[1048576] (4 MB)
#define OFF_SRC    8653952      // f32[16384]
#define OFF_TGT    8719488      // f32[16384]
#define OFF_NBR    8785024      // u16[4096*512] (4 MB)
#define OFF_CNT    12979328     // i32[4096]

// ---- kernel 0: dtype sniff ---------------------------------------------------
// mask[0,0] == 1.0 exactly. fp32 -> first u32 = 0x3F800000; bf16 -> otherwise.
__global__ void k_detect(const unsigned* __restrict__ mask_raw,
                         int* __restrict__ flag) {
    if (threadIdx.x == 0)
        *flag = (mask_raw[0] == 0x3F800000u) ? 1 : 0;   // 1 = fp32 inputs
}

// ---- kernel 1: W + b / a_left / a_right to f32 -------------------------------
__global__ __launch_bounds__(256) void k_cvt_w(
        const void* __restrict__ Wr, const void* __restrict__ br,
        const void* __restrict__ alr, const void* __restrict__ arr,
        const int* __restrict__ flag,
        float* __restrict__ WF, float* __restrict__ bias_f,
        float* __restrict__ al_f, float* __restrict__ ar_f) {
    int idx = blockIdx.x * 256 + threadIdx.x;   // 65536
    int fl = *flag;
    WF[idx] = fl ? ((const float*)Wr)[idx] : bits2f(((const unsigned short*)Wr)[idx]);
    if (idx < NCOL) {
        bias_f[idx] = fl ? ((const float*)br)[idx]  : bits2f(((const unsigned short*)br)[idx]);
        al_f[idx]   = fl ? ((const float*)alr)[idx] : bits2f(((const unsigned short*)alr)[idx]);
        ar_f[idx]   = fl ? ((const float*)arr)[idx] : bits2f(((const unsigned short*)arr)[idx]);
    }
}

// ---- kernel 2: per-row neighbor lists from the mask --------------------------
__global__ __launch_bounds__(256) void k_rows(
        const void* __restrict__ mask, const int* __restrict__ flag,
        unsigned short* __restrict__ nbr_g, int* __restrict__ cnt_g) {
    __shared__ int cnt;
    int n = blockIdx.x;
    if (threadIdx.x == 0) cnt = 0;
    __syncthreads();
    unsigned short* rn = nbr_g + (size_t)n * MAXNBR;
    if (*flag) {
        const uint4* p = (const uint4*)((const float*)mask + (size_t)n * NN);
        for (int i = threadIdx.x; i < NN / 4; i += 256) {
            uint4 v = p[i]; int base = i * 4;
            if (v.x) { int s = atomicAdd(&cnt, 1); if (s < MAXNBR) rn[s] = base + 0; }
            if (v.y) { int s = atomicAdd(&cnt, 1); if (s < MAXNBR) rn[s] = base + 1; }
            if (v.z) { int s = atomicAdd(&cnt, 1); if (s < MAXNBR) rn[s] = base + 2; }
            if (v.w) { int s = atomicAdd(&cnt, 1); if (s < MAXNBR) rn[s] = base + 3; }
        }
    } else {
        const uint4* p = (const uint4*)((const unsigned short*)mask + (size_t)n * NN);
        for (int i = threadIdx.x; i < NN / 8; i += 256) {
            uint4 v = p[i]; int base = i * 8;
            if (v.x & 0xFFFFu) { int s = atomicAdd(&cnt, 1); if (s < MAXNBR) rn[s] = base + 0; }
            if (v.x >> 16)     { int s = atomicAdd(&cnt, 1); if (s < MAXNBR) rn[s] = base + 1; }
            if (v.y & 0xFFFFu) { int s = atomicAdd(&cnt, 1); if (s < MAXNBR) rn[s] = base + 2; }
            if (v.y >> 16)     { int s = atomicAdd(&cnt, 1); if (s < MAXNBR) rn[s] = base + 3; }
            if (v.z & 0xFFFFu) { int s = atomicAdd(&cnt, 1); if (s < MAXNBR) rn[s] = base + 4; }
            if (v.z >> 16)     { int s = atomicAdd(&cnt, 1); if (s < MAXNBR) rn[s] = base + 5; }
            if (v.w & 0xFFFFu) { int s = atomicAdd(&cnt, 1); if (s < MAXNBR) rn[s] = base + 6; }
            if (v.w >> 16)     { int s = atomicAdd(&cnt, 1); if (s < MAXNBR) rn[s] = base + 7; }
        }
    }
    __syncthreads();
    if (threadIdx.x == 0) cnt_g[n] = cnt < MAXNBR ? cnt : MAXNBR;
}

// ---- kernel 3: x_proj = x@W+b (fp32 VALU GEMM) + fused src/tgt scores --------
// 512 blocks x 256 threads; each block: 8 rows, thread = output col, wave = head.
__global__ __launch_bounds__(256) void gat_gemm_valu(
        const void* __restrict__ xr, const int* __restrict__ flag,
        const float* __restrict__ WF, const float* __restrict__ bias,
        const float* __restrict__ alf, const float* __restrict__ arf,
        float* __restrict__ xp, float* __restrict__ src, float* __restrict__ tgt) {
    __shared__ float4 xs[8][64];
    int n0 = blockIdx.x * 8;
    if (*flag) {
        const float4* xq = (const float4*)xr;
        for (int t = threadIdx.x; t < 512; t += 256) {
            int r = t >> 6, q = t & 63;
            xs[r][q] = xq[(size_t)(n0 + r) * 64 + q];
        }
    } else {
        const ushort4* xq = (const ushort4*)xr;
        for (int t = threadIdx.x; t < 512; t += 256) {
            int r = t >> 6, q = t & 63;
            ushort4 u = xq[(size_t)(n0 + r) * 64 + q];
            float4 v; v.x = bits2f(u.x); v.y = bits2f(u.y); v.z = bits2f(u.z); v.w = bits2f(u.w);
            xs[r][q] = v;
        }
    }
    __syncthreads();
    int c = threadIdx.x;
    float acc[8] = {};
    for (int kk = 0; kk < 64; ++kk) {
        float w0 = WF[(4 * kk + 0) * NCOL + c];
        float w1 = WF[(4 * kk + 1) * NCOL + c];
        float w2 = WF[(4 * kk + 2) * NCOL + c];
        float w3 = WF[(4 * kk + 3) * NCOL + c];
        #pragma unroll
        for (int r = 0; r < 8; ++r) {
            float4 xv = xs[r][kk];
            acc[r] += xv.x * w0 + xv.y * w1 + xv.z * w2 + xv.w * w3;
        }
    }
    float bv = bias[c];
    float alv = alf[c], arv = arf[c];
    int wave = threadIdx.x >> 6;   // == head index for this col
    int lane = threadIdx.x & 63;
    #pragma unroll
    for (int r = 0; r < 8; ++r) {
        float o = acc[r] + bv;
        xp[(size_t)(n0 + r) * NCOL + c] = o;
        float sr = o * alv, tr = o * arv;
        #pragma unroll
        for (int off = 32; off; off >>= 1) {
            sr += __shfl_down(sr, off, 64);
            tr += __shfl_down(tr, off, 64);
        }
        if (lane == 0) {
            src[(n0 + r) * KH + wave] = sr;
            tgt[(n0 + r) * KH + wave] = tr;
        }
    }
}

// ---- kernel 4a: moments stage A — per-block partials, NO global atomics ------
__global__ __launch_bounds__(256) void k_moments_a(
        const float* __restrict__ src, const float* __restrict__ tgt,
        double2* __restrict__ partials) {
    const int total = NN * NN;
    const int stride = MOM_BLOCKS * 256;
    float s1 = 0.f, s2 = 0.f;
    for (int p = blockIdx.x * 256 + threadIdx.x; p < total; p += stride) {
        int n = p >> 12, m = p & 4095;
        float4 sv = ((const float4*)src)[n];
        float4 tv = ((const float4*)tgt)[m];
        float v0 = sv.x + tv.x; v0 = v0 > 0.f ? v0 : 0.2f * v0;
        float v1 = sv.y + tv.y; v1 = v1 > 0.f ? v1 : 0.2f * v1;
        float v2 = sv.z + tv.z; v2 = v2 > 0.f ? v2 : 0.2f * v2;
        float v3 = sv.w + tv.w; v3 = v3 > 0.f ? v3 : 0.2f * v3;
        s1 += v0 + v1 + v2 + v3;
        s2 += v0 * v0 + v1 * v1 + v2 * v2 + v3 * v3;
    }
    __shared__ double l1[256], l2[256];
    l1[threadIdx.x] = (double)s1;
    l2[threadIdx.x] = (double)s2;
    __syncthreads();
    for (int off = 128; off; off >>= 1) {
        if (threadIdx.x < off) {
            l1[threadIdx.x] += l1[threadIdx.x + off];
            l2[threadIdx.x] += l2[threadIdx.x + off];
        }
        __syncthreads();
    }
    if (threadIdx.x == 0) {
        double2 pr; pr.x = l1[0]; pr.y = l2[0];
        partials[blockIdx.x] = pr;
    }
}

// ---- kernel 4b: moments stage B — single block folds the partials ------------
__global__ __launch_bounds__(256) void k_moments_b(
        const double2* __restrict__ partials, double* __restrict__ sums) {
    double a = 0.0, b = 0.0;
    for (int i = threadIdx.x; i < MOM_BLOCKS; i += 256) {
        double2 pr = partials[i];
        a += pr.x; b += pr.y;
    }
    __shared__ double l1[256], l2[256];
    l1[threadIdx.x] = a;
    l2[threadIdx.x] = b;
    __syncthreads();
    for (int off = 128; off; off >>= 1) {
        if (threadIdx.x < off) {
            l1[threadIdx.x] += l1[threadIdx.x + off];
            l2[threadIdx.x] += l2[threadIdx.x + off];
        }
        __syncthreads();
    }
    if (threadIdx.x == 0) {
        sums[0] = l1[0];
        sums[1] = l2[0];
    }
}

// ---- kernel 5: per-row sparse softmax + aggregation + ELU (fp32 out) ---------
__global__ __launch_bounds__(256) void gat_aggregate(
        const unsigned short* __restrict__ nbr_g, const int* __restrict__ cnt_g,
        const float* __restrict__ xp,
        const float* __restrict__ src, const float* __restrict__ tgt,
        const double* __restrict__ sums,
        float* __restrict__ out) {
    __shared__ unsigned short snbr[MAXNBR];
    __shared__ float pls[MAXNBR * KH];
    __shared__ float invden[KH];
    int n = blockIdx.x;
    int c = cnt_g[n];
    for (int j = threadIdx.x; j < c; j += 256) snbr[j] = nbr_g[(size_t)n * MAXNBR + j];
    __syncthreads();

    double s = sums[0], ss = sums[1];
    const double tot = (double)NN * (double)NN * (double)KH;
    float mu = (float)(s / tot);
    float inv_sigma = (float)(1.0 / sqrt((ss - s * s / tot) / (tot - 1.0)));

    for (int t = threadIdx.x; t < c * KH; t += 256) {
        int j = t >> 2, k = t & 3;
        int m = snbr[j];
        float v = src[n * KH + k] + tgt[m * KH + k];
        v = v > 0.f ? v : 0.2f * v;
        pls[j * KH + k] = expf((v - mu) * inv_sigma);
    }
    __syncthreads();
    if (threadIdx.x < KH) {
        float d = 0.f;
        for (int j = 0; j < c; ++j) d += pls[j * KH + threadIdx.x];
        invden[threadIdx.x] = 1.0f / d;
    }
    __syncthreads();

    int col = threadIdx.x;
    int k = col >> 6;
    float acc = 0.f;
    for (int j = 0; j < c; ++j) {
        acc += pls[j * KH + k] * xp[(size_t)snbr[j] * NCOL + col];
    }
    acc *= invden[k];
    float o = acc > 0.f ? acc : expm1f(acc);
    out[(size_t)n * NCOL + col] = o;
}

extern "C" void kernel_launch(void* const* d_in, const int* in_sizes, int n_in,
                              void* d_out, int out_size, void* d_ws, size_t ws_size,
                              hipStream_t stream) {
    const void* x    = d_in[0];
    const void* mask = d_in[1];
    // d_in[2] = batch (int32) — unused by the reference math
    const void* W    = d_in[3];
    const void* b    = d_in[4];
    const void* al   = d_in[5];
    const void* ar   = d_in[6];

    char* ws = (char*)d_ws;
    double* sums = (double*)(ws + OFF_SUMS);
    int* flag = (int*)(ws + OFF_FLAG);
    double2* part = (double2*)(ws + OFF_PART);
    float* WF   = (float*)(ws + OFF_WF);
    float* bias = (float*)(ws + OFF_BIAS);
    float* alf  = (float*)(ws + OFF_AL);
    float* arf  = (float*)(ws + OFF_AR);
    float* xp   = (float*)(ws + OFF_XP);
    float* src  = (float*)(ws + OFF_SRC);
    float* tgt  = (float*)(ws + OFF_TGT);
    unsigned short* nbr = (unsigned short*)(ws + OFF_NBR);
    int* cntg = (int*)(ws + OFF_CNT);

    k_detect<<<1, 64, 0, stream>>>((const unsigned*)mask, flag);
    k_cvt_w<<<256, 256, 0, stream>>>(W, b, al, ar, flag, WF, bias, alf, arf);
    k_rows<<<4096, 256, 0, stream>>>(mask, flag, nbr, cntg);
    gat_gemm_valu<<<512, 256, 0, stream>>>(x, flag, WF, bias, alf, arf, xp, src, tgt);
    k_moments_a<<<MOM_BLOCKS, 256, 0, stream>>>(src, tgt, part);
    k_moments_b<<<1, 256, 0, stream>>>(part, sums);
    gat_aggregate<<<4096, 256, 0, stream>>>(nbr, cntg, xp, src, tgt, sums,
                                            (float*)d_out);
}

// Round 5
// 163.990 us; speedup vs baseline: 1.5741x; 1.0392x over previous
//
#include <hip/hip_runtime.h>
#include <hip/hip_bf16.h>
#include <math.h>

// Problem constants
#define NN 4096
#define FF 256
#define KH 4
#define FP 64
#define NCOL 256   // K*FP
#define MAXNBR 512
#define MOM_BLOCKS 2048

// bf16 -> f32 exact upcast
__device__ __forceinline__ float bits2f(unsigned b) {
    union { unsigned u; float f; } c; c.u = b << 16; return c.f;
}
// dtype sniff: mask[0,0]==1.0 exactly; fp32 iff first u32 == 0x3F800000
__device__ __forceinline__ int is_fp32(const void* mask) {
    return ((const unsigned*)mask)[0] == 0x3F800000u;
}

// Workspace layout (bytes)
#define OFF_SUMS   0            // double[2]
#define OFF_PART   128          // double2[2048] (32 KB)
#define OFF_XP     65536        // f32[1048576] (4 MB)
#define OFF_SRC    4259840      // f32[16384]
#define OFF_TGT    4325376      // f32[16384]

// ---- kernel 1: x_proj = x@W+b (fp32 VALU GEMM) + fused src/tgt scores --------
// 512 blocks x 256 threads; each block: 8 rows, thread = output col, wave = head.
__global__ __launch_bounds__(256) void gat_gemm_valu(
        const void* __restrict__ xr, const void* __restrict__ mask,
        const void* __restrict__ Wr, const void* __restrict__ br,
        const void* __restrict__ alr, const void* __restrict__ arr,
        float* __restrict__ xp, float* __restrict__ src, float* __restrict__ tgt) {
    const int fl = is_fp32(mask);
    __shared__ float4 xs[8][64];
    int n0 = blockIdx.x * 8;
    if (fl) {
        const float4* xq = (const float4*)xr;
        for (int t = threadIdx.x; t < 512; t += 256) {
            int r = t >> 6, q = t & 63;
            xs[r][q] = xq[(size_t)(n0 + r) * 64 + q];
        }
    } else {
        const ushort4* xq = (const ushort4*)xr;
        for (int t = threadIdx.x; t < 512; t += 256) {
            int r = t >> 6, q = t & 63;
            ushort4 u = xq[(size_t)(n0 + r) * 64 + q];
            float4 v; v.x = bits2f(u.x); v.y = bits2f(u.y); v.z = bits2f(u.z); v.w = bits2f(u.w);
            xs[r][q] = v;
        }
    }
    __syncthreads();
    int c = threadIdx.x;
    float acc[8] = {};
    if (fl) {
        const float* WF = (const float*)Wr;
        for (int kk = 0; kk < 64; ++kk) {
            float w0 = WF[(4 * kk + 0) * NCOL + c];
            float w1 = WF[(4 * kk + 1) * NCOL + c];
            float w2 = WF[(4 * kk + 2) * NCOL + c];
            float w3 = WF[(4 * kk + 3) * NCOL + c];
            #pragma unroll
            for (int r = 0; r < 8; ++r) {
                float4 xv = xs[r][kk];
                acc[r] += xv.x * w0 + xv.y * w1 + xv.z * w2 + xv.w * w3;
            }
        }
    } else {
        const unsigned short* WB = (const unsigned short*)Wr;
        for (int kk = 0; kk < 64; ++kk) {
            float w0 = bits2f(WB[(4 * kk + 0) * NCOL + c]);
            float w1 = bits2f(WB[(4 * kk + 1) * NCOL + c]);
            float w2 = bits2f(WB[(4 * kk + 2) * NCOL + c]);
            float w3 = bits2f(WB[(4 * kk + 3) * NCOL + c]);
            #pragma unroll
            for (int r = 0; r < 8; ++r) {
                float4 xv = xs[r][kk];
                acc[r] += xv.x * w0 + xv.y * w1 + xv.z * w2 + xv.w * w3;
            }
        }
    }
    float bv, alv, arv;
    if (fl) {
        bv  = ((const float*)br)[c];
        alv = ((const float*)alr)[c];
        arv = ((const float*)arr)[c];
    } else {
        bv  = bits2f(((const unsigned short*)br)[c]);
        alv = bits2f(((const unsigned short*)alr)[c]);
        arv = bits2f(((const unsigned short*)arr)[c]);
    }
    int wave = threadIdx.x >> 6;   // == head index for this col
    int lane = threadIdx.x & 63;
    #pragma unroll
    for (int r = 0; r < 8; ++r) {
        float o = acc[r] + bv;
        xp[(size_t)(n0 + r) * NCOL + c] = o;
        float sr = o * alv, tr = o * arv;
        #pragma unroll
        for (int off = 32; off; off >>= 1) {
            sr += __shfl_down(sr, off, 64);
            tr += __shfl_down(tr, off, 64);
        }
        if (lane == 0) {
            src[(n0 + r) * KH + wave] = sr;
            tgt[(n0 + r) * KH + wave] = tr;
        }
    }
}

// ---- kernel 2a: moments stage A — per-block partials, NO global atomics ------
__global__ __launch_bounds__(256) void k_moments_a(
        const float* __restrict__ src, const float* __restrict__ tgt,
        double2* __restrict__ partials) {
    const int total = NN * NN;
    const int stride = MOM_BLOCKS * 256;
    float s1 = 0.f, s2 = 0.f;
    for (int p = blockIdx.x * 256 + threadIdx.x; p < total; p += stride) {
        int n = p >> 12, m = p & 4095;
        float4 sv = ((const float4*)src)[n];
        float4 tv = ((const float4*)tgt)[m];
        float v0 = sv.x + tv.x; v0 = v0 > 0.f ? v0 : 0.2f * v0;
        float v1 = sv.y + tv.y; v1 = v1 > 0.f ? v1 : 0.2f * v1;
        float v2 = sv.z + tv.z; v2 = v2 > 0.f ? v2 : 0.2f * v2;
        float v3 = sv.w + tv.w; v3 = v3 > 0.f ? v3 : 0.2f * v3;
        s1 += v0 + v1 + v2 + v3;
        s2 += v0 * v0 + v1 * v1 + v2 * v2 + v3 * v3;
    }
    __shared__ double l1[256], l2[256];
    l1[threadIdx.x] = (double)s1;
    l2[threadIdx.x] = (double)s2;
    __syncthreads();
    for (int off = 128; off; off >>= 1) {
        if (threadIdx.x < off) {
            l1[threadIdx.x] += l1[threadIdx.x + off];
            l2[threadIdx.x] += l2[threadIdx.x + off];
        }
        __syncthreads();
    }
    if (threadIdx.x == 0) {
        double2 pr; pr.x = l1[0]; pr.y = l2[0];
        partials[blockIdx.x] = pr;
    }
}

// ---- kernel 2b: moments stage B — single block folds the partials ------------
__global__ __launch_bounds__(256) void k_moments_b(
        const double2* __restrict__ partials, double* __restrict__ sums) {
    double a = 0.0, b = 0.0;
    for (int i = threadIdx.x; i < MOM_BLOCKS; i += 256) {
        double2 pr = partials[i];
        a += pr.x; b += pr.y;
    }
    __shared__ double l1[256], l2[256];
    l1[threadIdx.x] = a;
    l2[threadIdx.x] = b;
    __syncthreads();
    for (int off = 128; off; off >>= 1) {
        if (threadIdx.x < off) {
            l1[threadIdx.x] += l1[threadIdx.x + off];
            l2[threadIdx.x] += l2[threadIdx.x + off];
        }
        __syncthreads();
    }
    if (threadIdx.x == 0) {
        sums[0] = l1[0];
        sums[1] = l2[0];
    }
}

// ---- kernel 3: mask scan + sparse softmax + aggregation + ELU (fp32 out) -----
// One block (256 threads) per row n. Scans the mask row inline (no nbr array).
__global__ __launch_bounds__(256) void gat_aggregate(
        const void* __restrict__ mask,
        const float* __restrict__ xp,
        const float* __restrict__ src, const float* __restrict__ tgt,
        const double* __restrict__ sums,
        float* __restrict__ out) {
    __shared__ unsigned short snbr[MAXNBR];
    __shared__ float pls[MAXNBR * KH];
    __shared__ float invden[KH];
    __shared__ int cnt;
    const int fl = is_fp32(mask);
    int n = blockIdx.x;
    if (threadIdx.x == 0) cnt = 0;
    __syncthreads();

    if (fl) {
        const uint4* p = (const uint4*)((const float*)mask + (size_t)n * NN);
        for (int i = threadIdx.x; i < NN / 4; i += 256) {
            uint4 v = p[i]; int base = i * 4;
            if (v.x) { int s = atomicAdd(&cnt, 1); if (s < MAXNBR) snbr[s] = base + 0; }
            if (v.y) { int s = atomicAdd(&cnt, 1); if (s < MAXNBR) snbr[s] = base + 1; }
            if (v.z) { int s = atomicAdd(&cnt, 1); if (s < MAXNBR) snbr[s] = base + 2; }
            if (v.w) { int s = atomicAdd(&cnt, 1); if (s < MAXNBR) snbr[s] = base + 3; }
        }
    } else {
        const uint4* p = (const uint4*)((const unsigned short*)mask + (size_t)n * NN);
        for (int i = threadIdx.x; i < NN / 8; i += 256) {
            uint4 v = p[i]; int base = i * 8;
            if (v.x & 0xFFFFu) { int s = atomicAdd(&cnt, 1); if (s < MAXNBR) snbr[s] = base + 0; }
            if (v.x >> 16)     { int s = atomicAdd(&cnt, 1); if (s < MAXNBR) snbr[s] = base + 1; }
            if (v.y & 0xFFFFu) { int s = atomicAdd(&cnt, 1); if (s < MAXNBR) snbr[s] = base + 2; }
            if (v.y >> 16)     { int s = atomicAdd(&cnt, 1); if (s < MAXNBR) snbr[s] = base + 3; }
            if (v.z & 0xFFFFu) { int s = atomicAdd(&cnt, 1); if (s < MAXNBR) snbr[s] = base + 4; }
            if (v.z >> 16)     { int s = atomicAdd(&cnt, 1); if (s < MAXNBR) snbr[s] = base + 5; }
            if (v.w & 0xFFFFu) { int s = atomicAdd(&cnt, 1); if (s < MAXNBR) snbr[s] = base + 6; }
            if (v.w >> 16)     { int s = atomicAdd(&cnt, 1); if (s < MAXNBR) snbr[s] = base + 7; }
        }
    }
    __syncthreads();
    int c = cnt < MAXNBR ? cnt : MAXNBR;

    double s = sums[0], ss = sums[1];
    const double tot = (double)NN * (double)NN * (double)KH;
    float mu = (float)(s / tot);
    float inv_sigma = (float)(1.0 / sqrt((ss - s * s / tot) / (tot - 1.0)));

    for (int t = threadIdx.x; t < c * KH; t += 256) {
        int j = t >> 2, k = t & 3;
        int m = snbr[j];
        float v = src[n * KH + k] + tgt[m * KH + k];
        v = v > 0.f ? v : 0.2f * v;
        pls[j * KH + k] = expf((v - mu) * inv_sigma);
    }
    __syncthreads();
    if (threadIdx.x < KH) {
        float d = 0.f;
        for (int j = 0; j < c; ++j) d += pls[j * KH + threadIdx.x];
        invden[threadIdx.x] = 1.0f / d;
    }
    __syncthreads();

    int col = threadIdx.x;
    int k = col >> 6;
    float acc = 0.f;
    for (int j = 0; j < c; ++j) {
        acc += pls[j * KH + k] * xp[(size_t)snbr[j] * NCOL + col];
    }
    acc *= invden[k];
    float o = acc > 0.f ? acc : expm1f(acc);
    out[(size_t)n * NCOL + col] = o;
}

extern "C" void kernel_launch(void* const* d_in, const int* in_sizes, int n_in,
                              void* d_out, int out_size, void* d_ws, size_t ws_size,
                              hipStream_t stream) {
    const void* x    = d_in[0];
    const void* mask = d_in[1];
    // d_in[2] = batch (int32) — unused by the reference math
    const void* W    = d_in[3];
    const void* b    = d_in[4];
    const void* al   = d_in[5];
    const void* ar   = d_in[6];

    char* ws = (char*)d_ws;
    double* sums = (double*)(ws + OFF_SUMS);
    double2* part = (double2*)(ws + OFF_PART);
    float* xp   = (float*)(ws + OFF_XP);
    float* src  = (float*)(ws + OFF_SRC);
    float* tgt  = (float*)(ws + OFF_TGT);

    gat_gemm_valu<<<512, 256, 0, stream>>>(x, mask, W, b, al, ar, xp, src, tgt);
    k_moments_a<<<MOM_BLOCKS, 256, 0, stream>>>(src, tgt, part);
    k_moments_b<<<1, 256, 0, stream>>>(part, sums);
    gat_aggregate<<<4096, 256, 0, stream>>>(mask, xp, src, tgt, sums,
                                            (float*)d_out);
}